// Round 5
// baseline (179.005 us; speedup 1.0000x reference)
//
#include <hip/hip_runtime.h>
#include <math.h>

typedef short short8 __attribute__((ext_vector_type(8)));
typedef float float4_t __attribute__((ext_vector_type(4)));
typedef unsigned uint2_t __attribute__((ext_vector_type(2)));
typedef unsigned short ushort_t;

#define BH   32
#define N_   2048
#define D_   64
#define NCH  32
#define LDP  72
#define KV_ELEMS (BH * N_ * D_)
// d_ws: Kf [0,8M) | Vf [8M,16M) | msk [16M,16.5M)
#define OFF_VF  (KV_ELEMS * 2)
#define OFF_MSK (KV_ELEMS * 4)
#define QSCALE 0.18033688f      // 0.125*log2(e): exp(s/8) == exp2(s*QSCALE)

__device__ __forceinline__ unsigned pack_bf16(float a, float b) {
  union { float f; unsigned u; } ua{a}, ub{b};
  return __builtin_amdgcn_perm(ub.u + 0x8000u, ua.u + 0x8000u, 0x07060302u);
}

__device__ __forceinline__ void gload_lds16(const ushort_t* g, ushort_t* l) {
  // async global->LDS, 16B/lane, lane-linear dest (fragment-linear layout)
  __builtin_amdgcn_global_load_lds(
      (const __attribute__((address_space(1))) unsigned int*)(g),
      (__attribute__((address_space(3))) unsigned int*)(l), 16, 0, 0);
}

// ---------------- prep (r8-verified, unchanged): fragment-linear Kf/Vf + bitmask ----------------
__global__ __launch_bounds__(256) void prep_kernel(
    const float* __restrict__ K, const float* __restrict__ V,
    const int* __restrict__ adj, ushort_t* __restrict__ Kf,
    ushort_t* __restrict__ Vf, unsigned long long* __restrict__ msk) {
  __shared__ __align__(16) float Tc[64 * 68];
  const int blk = blockIdx.x, t = threadIdx.x;

  if (blk < 2048) {
    const bool isK = blk < 1024;
    const int b = isK ? blk : blk - 1024;
    const float* src = (isK ? K : V) + (b >> 5) * (N_ * D_) + (b & 31) * 64 * D_;
#pragma unroll
    for (int i = 0; i < 4; ++i) {
      int idx = i * 256 + t;
      int row = idx >> 4, c4 = (idx & 15) * 4;
      *(float4_t*)&Tc[row * 68 + c4] = *(const float4_t*)(src + row * D_ + c4);
    }
    __syncthreads();
    ushort_t* dst = (isK ? Kf : Vf) + b * 4096;
#pragma unroll
    for (int e = 0; e < 2; ++e) {
      int u = t * 2 + e;
      int g = u >> 6, lane = u & 63;
      int ks = g >> 2, quad = lane >> 4, l16 = lane & 15;
      float v[8];
      if (isK) {
        int nt = g & 3;
        const float* rp = &Tc[(nt * 16 + l16) * 68 + ks * 32 + quad * 8];
        float4_t a = *(const float4_t*)(rp);
        float4_t bq = *(const float4_t*)(rp + 4);
#pragma unroll
        for (int j = 0; j < 4; ++j) { v[j] = a[j]; v[4 + j] = bq[j]; }
      } else {
        int dt = g & 3, d = dt * 16 + l16;
#pragma unroll
        for (int j = 0; j < 8; ++j) {
          int key = 16 * (j & 3) + ks * 8 + quad * 2 + (j >> 2);
          v[j] = Tc[key * 68 + d];
        }
      }
      union { short8 s; unsigned u4[4]; } h;
      h.u4[0] = pack_bf16(v[0], v[1]); h.u4[1] = pack_bf16(v[2], v[3]);
      h.u4[2] = pack_bf16(v[4], v[5]); h.u4[3] = pack_bf16(v[6], v[7]);
      *(short8*)(dst + u * 8) = h.s;
    }
  } else {
    const int row = (blk - 2048) * 4 + (t >> 6);
    const int lane = t & 63;
    unsigned long long keep = 0;
#pragma unroll 8
    for (int i = 0; i < 32; ++i) {
      int a = adj[row * N_ + i * 64 + lane];
      unsigned long long b = __ballot(a > 0);
      if (lane == i) keep = b;
    }
    if (lane < 32) msk[row * 32 + lane] = keep;
  }
}

// -------- main v5: v4 + mask prefetch 1 chunk ahead (reg dbuf) + setprio(MFMA) --------
__global__ __launch_bounds__(256, 2) void attn_main(
    const float* __restrict__ Q, const ushort_t* __restrict__ Kf,
    const ushort_t* __restrict__ Vf, const unsigned long long* __restrict__ msk,
    float* __restrict__ O) {
  __shared__ __align__(16) ushort_t kv[2][8192];           // [K 8KB | V 8KB] x2, 32KB
  __shared__ __align__(16) ushort_t lds_p[4][2][16 * LDP]; // wave-private P, 18KB

  const int t    = threadIdx.x;
  const int w    = t >> 6;                   // 0..3
  const int lane = t & 63;
  const int quad = lane >> 4;
  const int l16  = lane & 15;
  const int bh   = blockIdx.x & (BH - 1);
  const int qt   = blockIdx.x >> 5;          // 0..15
  const int base = bh * (N_ * D_);
  const int qrow0 = qt * 128 + w * 32;       // 32 rows per wave, 128 per block

  const ushort_t* Kfb = Kf + (bh * 32) * 4096;
  const ushort_t* Vfb = Vf + (bh * 32) * 4096;
  const unsigned long long* mr[2] = {
    msk + (qrow0 + quad * 4) * 32,
    msk + (qrow0 + 16 + quad * 4) * 32
  };

  // Q fragments x2 groups, QSCALE folded (A-layout m=l16, k=ks*32+quad*8+j)
  short8 qf[2][2];
#pragma unroll
  for (int qg = 0; qg < 2; ++qg)
#pragma unroll
    for (int ks = 0; ks < 2; ++ks) {
      const float* qp = Q + base + (qrow0 + qg * 16 + l16) * D_ + ks * 32 + quad * 8;
      float4_t f0 = *(const float4_t*)(qp);
      float4_t f1 = *(const float4_t*)(qp + 4);
      union { short8 s; unsigned u[4]; } h;
      h.u[0] = pack_bf16(f0[0] * QSCALE, f0[1] * QSCALE);
      h.u[1] = pack_bf16(f0[2] * QSCALE, f0[3] * QSCALE);
      h.u[2] = pack_bf16(f1[0] * QSCALE, f1[1] * QSCALE);
      h.u[3] = pack_bf16(f1[2] * QSCALE, f1[3] * QSCALE);
      qf[qg][ks] = h.s;
    }

  // constant ones B-fragment (bf16 1.0) for lsum-via-MFMA
  short8 ones;
#pragma unroll
  for (int j = 0; j < 8; ++j) ones[j] = (short)0x3F80;

  float4_t oacc[2][4];    // O, C-layout
  float4_t osum[2];       // row-sums of masked P (all 16 cols identical)
#pragma unroll
  for (int qg = 0; qg < 2; ++qg) {
#pragma unroll
    for (int dt = 0; dt < 4; ++dt) oacc[qg][dt] = (float4_t){0.f, 0.f, 0.f, 0.f};
    osum[qg] = (float4_t){0.f, 0.f, 0.f, 0.f};
  }

  const int fo = lane * 8;   // lane-linear fragment offset (16B/lane)

  // cooperative stage of chunk c into kv[nb]: wave w (0..3) moves
  // K bytes [w*2KB,+2KB) and V bytes [w*2KB,+2KB): 4 x global_load_lds dwordx4
#define STAGE(nb, c)                                                           \
  do {                                                                         \
    const ushort_t* _sk = Kfb + (c)*4096 + w * 1024 + lane * 8;                \
    const ushort_t* _sv = Vfb + (c)*4096 + w * 1024 + lane * 8;                \
    ushort_t* _dk = &kv[nb][w * 1024];                                         \
    ushort_t* _dv = &kv[nb][4096 + w * 1024];                                  \
    gload_lds16(_sk, _dk);                                                     \
    gload_lds16(_sk + 512, _dk + 512);                                         \
    gload_lds16(_sv, _dv);                                                     \
    gload_lds16(_sv + 512, _dv + 512);                                         \
  } while (0)

  // mask prefetch: loads for chunk c land a full chunk before the exp phase
  // that consumes them (masks are read-once -> L2/L3-miss latency otherwise
  // stalls all phase-locked waves at the exp phase). Parity index is
  // compile-time under the unroll-2 loop (no scratch, rule #20).
  unsigned long long mw[2][2][4];   // [parity][qg][r]
#define LOADMASK(nb, c)                                                        \
  do {                                                                         \
    _Pragma("unroll") for (int _qg = 0; _qg < 2; ++_qg)                        \
    _Pragma("unroll") for (int _r = 0; _r < 4; ++_r)                           \
        mw[nb][_qg][_r] = mr[_qg][_r * 32 + (c)];                              \
  } while (0)

  LOADMASK(0, 0);
  STAGE(0, 0);   // prologue

#pragma unroll 2
  for (int c = 0; c < NCH; ++c) {
    const int cur = c & 1;
    // implicit vmcnt(0)+lgkmcnt(0) drain: stage(c) + mask(c) landed for ALL waves
    __syncthreads();

    // issue next chunk's mask loads + K/V stage first: a full chunk of cover
    if (c + 1 < NCH) {
      LOADMASK(cur ^ 1, c + 1);
      STAGE(cur ^ 1, c + 1);
    }

    const ushort_t* kb = &kv[cur][0];
    const ushort_t* vb = &kv[cur][4096];

    // ---- S-MFMAs: each K fragment read ONCE, used by both q-groups ----
    float4_t sacc[2][4];
#pragma unroll
    for (int qg = 0; qg < 2; ++qg)
#pragma unroll
      for (int nt = 0; nt < 4; ++nt) sacc[qg][nt] = (float4_t){0.f, 0.f, 0.f, 0.f};
    __builtin_amdgcn_s_setprio(1);
#pragma unroll
    for (int ks = 0; ks < 2; ++ks)
#pragma unroll
      for (int nt = 0; nt < 4; ++nt) {
        short8 kfr = *(const short8*)(kb + (ks * 4 + nt) * 512 + fo);
        sacc[0][nt] = __builtin_amdgcn_mfma_f32_16x16x32_bf16(qf[0][ks], kfr, sacc[0][nt], 0, 0, 0);
        sacc[1][nt] = __builtin_amdgcn_mfma_f32_16x16x32_bf16(qf[1][ks], kfr, sacc[1][nt], 0, 0, 0);
      }
    __builtin_amdgcn_s_setprio(0);

    // ---- mask + exp -> P to wave-private LDS (masks already in registers) ----
#pragma unroll
    for (int qg = 0; qg < 2; ++qg)
#pragma unroll
      for (int r = 0; r < 4; ++r) {
        unsigned long long sh = mw[cur][qg][r] >> l16;
        unsigned lo = (unsigned)sh, hi = (unsigned)(sh >> 32);
        float p0 = (lo & 1u)       ? exp2f(sacc[qg][0][r]) : 0.f;
        float p1 = (lo & 0x10000u) ? exp2f(sacc[qg][1][r]) : 0.f;
        float p2 = (hi & 1u)       ? exp2f(sacc[qg][2][r]) : 0.f;
        float p3 = (hi & 0x10000u) ? exp2f(sacc[qg][3][r]) : 0.f;
        uint2_t d2;
        d2.x = pack_bf16(p0, p1);
        d2.y = pack_bf16(p2, p3);
        *(uint2_t*)&lds_p[w][qg][(quad * 4 + r) * LDP + (l16 << 2)] = d2;
      }
    // no barrier: wave-private, ordered by lgkmcnt

    // ---- O += P V ; osum += P * ones : each V fragment read ONCE ----
    __builtin_amdgcn_s_setprio(1);
#pragma unroll
    for (int ks = 0; ks < 2; ++ks) {
      short8 pf0 = *(const short8*)&lds_p[w][0][l16 * LDP + ks * 32 + quad * 8];
      short8 pf1 = *(const short8*)&lds_p[w][1][l16 * LDP + ks * 32 + quad * 8];
#pragma unroll
      for (int dt = 0; dt < 4; ++dt) {
        short8 vfr = *(const short8*)(vb + (ks * 4 + dt) * 512 + fo);
        oacc[0][dt] = __builtin_amdgcn_mfma_f32_16x16x32_bf16(pf0, vfr, oacc[0][dt], 0, 0, 0);
        oacc[1][dt] = __builtin_amdgcn_mfma_f32_16x16x32_bf16(pf1, vfr, oacc[1][dt], 0, 0, 0);
      }
      osum[0] = __builtin_amdgcn_mfma_f32_16x16x32_bf16(pf0, ones, osum[0], 0, 0, 0);
      osum[1] = __builtin_amdgcn_mfma_f32_16x16x32_bf16(pf1, ones, osum[1], 0, 0, 0);
    }
    __builtin_amdgcn_s_setprio(0);
  }

  // ---- epilogue: rowsum already per-lane in osum (all cols equal) ----
#pragma unroll
  for (int qg = 0; qg < 2; ++qg)
#pragma unroll
    for (int r = 0; r < 4; ++r) {
      float inv = 1.f / osum[qg][r];
      int qi = qrow0 + qg * 16 + quad * 4 + r;
#pragma unroll
      for (int dt = 0; dt < 4; ++dt)
        O[base + qi * D_ + dt * 16 + l16] = oacc[qg][dt][r] * inv;
    }
}

extern "C" void kernel_launch(void* const* d_in, const int* in_sizes, int n_in,
                              void* d_out, int out_size, void* d_ws, size_t ws_size,
                              hipStream_t stream) {
  const float* Q  = (const float*)d_in[0];
  const float* K  = (const float*)d_in[1];
  const float* V  = (const float*)d_in[2];
  const int* adj  = (const int*)d_in[3];
  float* O        = (float*)d_out;
  ushort_t* Kf    = (ushort_t*)d_ws;
  ushort_t* Vf    = (ushort_t*)((char*)d_ws + OFF_VF);
  unsigned long long* msk = (unsigned long long*)((char*)d_ws + OFF_MSK);

  prep_kernel<<<2560, 256, 0, stream>>>(K, V, adj, Kf, Vf, msk);
  attn_main<<<512, 256, 0, stream>>>(Q, Kf, Vf, msk, O);   // 2048 waves, 8/CU
}

// Round 6
// 154.545 us; speedup vs baseline: 1.1583x; 1.1583x over previous
//
#include <hip/hip_runtime.h>
#include <math.h>

typedef short short8 __attribute__((ext_vector_type(8)));
typedef float float4_t __attribute__((ext_vector_type(4)));
typedef unsigned uint2_t __attribute__((ext_vector_type(2)));
typedef unsigned short ushort_t;

#define BH   32
#define N_   2048
#define D_   64
#define NCH  32
#define LDP  72
#define KV_ELEMS (BH * N_ * D_)
// d_ws: Kf [0,8M) | Vf [8M,16M) | msk [16M,16.5M)
#define OFF_VF  (KV_ELEMS * 2)
#define OFF_MSK (KV_ELEMS * 4)
#define QSCALE 0.18033688f      // 0.125*log2(e): exp(s/8) == exp2(s*QSCALE)

__device__ __forceinline__ unsigned pack_bf16(float a, float b) {
  union { float f; unsigned u; } ua{a}, ub{b};
  return __builtin_amdgcn_perm(ub.u + 0x8000u, ua.u + 0x8000u, 0x07060302u);
}

__device__ __forceinline__ void gload_lds16(const ushort_t* g, ushort_t* l) {
  // async global->LDS, 16B/lane, lane-linear dest (fragment-linear layout)
  __builtin_amdgcn_global_load_lds(
      (const __attribute__((address_space(1))) unsigned int*)(g),
      (__attribute__((address_space(3))) unsigned int*)(l), 16, 0, 0);
}

// ---------------- prep (r8-verified, unchanged): fragment-linear Kf/Vf + bitmask ----------------
__global__ __launch_bounds__(256) void prep_kernel(
    const float* __restrict__ K, const float* __restrict__ V,
    const int* __restrict__ adj, ushort_t* __restrict__ Kf,
    ushort_t* __restrict__ Vf, unsigned long long* __restrict__ msk) {
  __shared__ __align__(16) float Tc[64 * 68];
  const int blk = blockIdx.x, t = threadIdx.x;

  if (blk < 2048) {
    const bool isK = blk < 1024;
    const int b = isK ? blk : blk - 1024;
    const float* src = (isK ? K : V) + (b >> 5) * (N_ * D_) + (b & 31) * 64 * D_;
#pragma unroll
    for (int i = 0; i < 4; ++i) {
      int idx = i * 256 + t;
      int row = idx >> 4, c4 = (idx & 15) * 4;
      *(float4_t*)&Tc[row * 68 + c4] = *(const float4_t*)(src + row * D_ + c4);
    }
    __syncthreads();
    ushort_t* dst = (isK ? Kf : Vf) + b * 4096;
#pragma unroll
    for (int e = 0; e < 2; ++e) {
      int u = t * 2 + e;
      int g = u >> 6, lane = u & 63;
      int ks = g >> 2, quad = lane >> 4, l16 = lane & 15;
      float v[8];
      if (isK) {
        int nt = g & 3;
        const float* rp = &Tc[(nt * 16 + l16) * 68 + ks * 32 + quad * 8];
        float4_t a = *(const float4_t*)(rp);
        float4_t bq = *(const float4_t*)(rp + 4);
#pragma unroll
        for (int j = 0; j < 4; ++j) { v[j] = a[j]; v[4 + j] = bq[j]; }
      } else {
        int dt = g & 3, d = dt * 16 + l16;
#pragma unroll
        for (int j = 0; j < 8; ++j) {
          int key = 16 * (j & 3) + ks * 8 + quad * 2 + (j >> 2);
          v[j] = Tc[key * 68 + d];
        }
      }
      union { short8 s; unsigned u4[4]; } h;
      h.u4[0] = pack_bf16(v[0], v[1]); h.u4[1] = pack_bf16(v[2], v[3]);
      h.u4[2] = pack_bf16(v[4], v[5]); h.u4[3] = pack_bf16(v[6], v[7]);
      *(short8*)(dst + u * 8) = h.s;
    }
  } else {
    const int row = (blk - 2048) * 4 + (t >> 6);
    const int lane = t & 63;
    unsigned long long keep = 0;
#pragma unroll 8
    for (int i = 0; i < 32; ++i) {
      int a = adj[row * N_ + i * 64 + lane];
      unsigned long long b = __ballot(a > 0);
      if (lane == i) keep = b;
    }
    if (lane < 32) msk[row * 32 + lane] = keep;
  }
}

// -------- main v6: r2 structure (8 waves/block share LDS-staged K/V, 16 rows/wave)
//          + VALU-trimmed exp phase: sext-bit masks AND'd on f32 bits, bare v_exp --------
__global__ __launch_bounds__(512) void attn_main(
    const float* __restrict__ Q, const ushort_t* __restrict__ Kf,
    const ushort_t* __restrict__ Vf, const unsigned long long* __restrict__ msk,
    float* __restrict__ O) {
  __shared__ __align__(16) ushort_t kv[2][8192];        // [K 8KB | V 8KB] x2, 32KB
  __shared__ __align__(16) ushort_t lds_p[8][16 * LDP]; // wave-private P, 18KB

  const int t    = threadIdx.x;
  const int w    = t >> 6;                   // 0..7
  const int lane = t & 63;
  const int quad = lane >> 4;
  const int l16  = lane & 15;
  const int bh   = blockIdx.x & (BH - 1);
  const int qt   = blockIdx.x >> 5;          // 0..15
  const int base = bh * (N_ * D_);
  const int qrow0 = qt * 128 + w * 16;       // 16 rows per wave, 128 per block

  const ushort_t* Kfb = Kf + (bh * 32) * 4096;
  const ushort_t* Vfb = Vf + (bh * 32) * 4096;
  const unsigned long long* mr = msk + (qrow0 + quad * 4) * 32;

  // Q fragments, QSCALE folded (A-layout m=l16, k=ks*32+quad*8+j)
  short8 qf[2];
#pragma unroll
  for (int ks = 0; ks < 2; ++ks) {
    const float* qp = Q + base + (qrow0 + l16) * D_ + ks * 32 + quad * 8;
    float4_t f0 = *(const float4_t*)(qp);
    float4_t f1 = *(const float4_t*)(qp + 4);
    union { short8 s; unsigned u[4]; } h;
    h.u[0] = pack_bf16(f0[0] * QSCALE, f0[1] * QSCALE);
    h.u[1] = pack_bf16(f0[2] * QSCALE, f0[3] * QSCALE);
    h.u[2] = pack_bf16(f1[0] * QSCALE, f1[1] * QSCALE);
    h.u[3] = pack_bf16(f1[2] * QSCALE, f1[3] * QSCALE);
    qf[ks] = h.s;
  }

  // constant ones B-fragment (bf16 1.0) for lsum-via-MFMA
  short8 ones;
#pragma unroll
  for (int j = 0; j < 8; ++j) ones[j] = (short)0x3F80;

  float4_t oacc[4];
  float4_t osum;
#pragma unroll
  for (int dt = 0; dt < 4; ++dt) oacc[dt] = (float4_t){0.f, 0.f, 0.f, 0.f};
  osum = (float4_t){0.f, 0.f, 0.f, 0.f};

  const int fo = lane * 8;   // lane-linear fragment offset (16B/lane)

  // cooperative stage of chunk c into kv[nb]: wave w moves bytes [w*2KB, +2KB)
  // (w<4 -> K chunk, w>=4 -> V chunk); 2 x global_load_lds dwordx4 per wave
#define STAGE(nb, c)                                                          \
  do {                                                                        \
    const ushort_t* _s = (w < 4 ? Kfb + (c)*4096 + w * 1024                   \
                                : Vfb + (c)*4096 + (w - 4) * 1024) + lane * 8;\
    ushort_t* _d = &kv[nb][w * 1024];                                         \
    gload_lds16(_s, _d);                                                      \
    gload_lds16(_s + 512, _d + 512);                                          \
  } while (0)

  STAGE(0, 0);   // prologue

#pragma unroll 2
  for (int c = 0; c < NCH; ++c) {
    const int cur = c & 1;
    // implicit vmcnt(0)+lgkmcnt(0) drain: stage(c) landed for ALL waves
    __syncthreads();

    // mask words first (so their wait leaves next stage loads in flight)
    unsigned long long mw[4];
#pragma unroll
    for (int r = 0; r < 4; ++r) mw[r] = mr[r * 32 + c];

    if (c + 1 < NCH) STAGE(cur ^ 1, c + 1);

    const ushort_t* kb = &kv[cur][0];
    const ushort_t* vb = &kv[cur][4096];

    // ---- S-MFMAs from LDS fragments ----
    float4_t sacc[4];
#pragma unroll
    for (int nt = 0; nt < 4; ++nt) sacc[nt] = (float4_t){0.f, 0.f, 0.f, 0.f};
#pragma unroll
    for (int ks = 0; ks < 2; ++ks)
#pragma unroll
      for (int nt = 0; nt < 4; ++nt) {
        short8 kfr = *(const short8*)(kb + (ks * 4 + nt) * 512 + fo);
        sacc[nt] = __builtin_amdgcn_mfma_f32_16x16x32_bf16(qf[ks], kfr, sacc[nt], 0, 0, 0);
      }

    // ---- mask + exp -> P (VALU-trimmed):
    //   mask = sign-extended bit (v_bfe_i32 fold) AND'd onto f32 bits (+0.0f),
    //   bare v_exp_f32 via builtin (inputs bounded, no libm range fixup) ----
#pragma unroll
    for (int r = 0; r < 4; ++r) {
      unsigned long long sh = mw[r] >> l16;
      unsigned lo = (unsigned)sh, hi = (unsigned)(sh >> 32);
      unsigned m0 = (unsigned)(((int)(lo << 31)) >> 31);   // sext(bit 0)
      unsigned m1 = (unsigned)(((int)(lo << 15)) >> 31);   // sext(bit 16)
      unsigned m2 = (unsigned)(((int)(hi << 31)) >> 31);   // sext(bit 32)
      unsigned m3 = (unsigned)(((int)(hi << 15)) >> 31);   // sext(bit 48)
      union { float f; unsigned u; } e0, e1, e2, e3;
      e0.f = __builtin_amdgcn_exp2f(sacc[0][r]); e0.u &= m0;
      e1.f = __builtin_amdgcn_exp2f(sacc[1][r]); e1.u &= m1;
      e2.f = __builtin_amdgcn_exp2f(sacc[2][r]); e2.u &= m2;
      e3.f = __builtin_amdgcn_exp2f(sacc[3][r]); e3.u &= m3;
      uint2_t d2;
      d2.x = pack_bf16(e0.f, e1.f);   // masked-zero survives: 0x0+0x8000 -> hi half 0
      d2.y = pack_bf16(e2.f, e3.f);
      *(uint2_t*)&lds_p[w][(quad * 4 + r) * LDP + (l16 << 2)] = d2;
    }
    // no barrier: wave-private, ordered by lgkmcnt

    // ---- O += P V ; osum += P * ones ----
#pragma unroll
    for (int ks = 0; ks < 2; ++ks) {
      short8 pf = *(const short8*)&lds_p[w][l16 * LDP + ks * 32 + quad * 8];
#pragma unroll
      for (int dt = 0; dt < 4; ++dt) {
        short8 vfr = *(const short8*)(vb + (ks * 4 + dt) * 512 + fo);
        oacc[dt] = __builtin_amdgcn_mfma_f32_16x16x32_bf16(pf, vfr, oacc[dt], 0, 0, 0);
      }
      osum = __builtin_amdgcn_mfma_f32_16x16x32_bf16(pf, ones, osum, 0, 0, 0);
    }
  }

  // ---- epilogue: rowsum already per-lane in osum (all cols equal) ----
#pragma unroll
  for (int r = 0; r < 4; ++r) {
    float inv = 1.f / osum[r];
    int qi = qrow0 + quad * 4 + r;
#pragma unroll
    for (int dt = 0; dt < 4; ++dt)
      O[base + qi * D_ + dt * 16 + l16] = oacc[dt][r] * inv;
  }
}

extern "C" void kernel_launch(void* const* d_in, const int* in_sizes, int n_in,
                              void* d_out, int out_size, void* d_ws, size_t ws_size,
                              hipStream_t stream) {
  const float* Q  = (const float*)d_in[0];
  const float* K  = (const float*)d_in[1];
  const float* V  = (const float*)d_in[2];
  const int* adj  = (const int*)d_in[3];
  float* O        = (float*)d_out;
  ushort_t* Kf    = (ushort_t*)d_ws;
  ushort_t* Vf    = (ushort_t*)((char*)d_ws + OFF_VF);
  unsigned long long* msk = (unsigned long long*)((char*)d_ws + OFF_MSK);

  prep_kernel<<<2560, 256, 0, stream>>>(K, V, adj, Kf, Vf, msk);
  attn_main<<<512, 512, 0, stream>>>(Q, Kf, Vf, msk, O);   // 4096 waves, 16/CU
}

// Round 8
// 154.182 us; speedup vs baseline: 1.1610x; 1.0024x over previous
//
#include <hip/hip_runtime.h>
#include <math.h>

typedef short short8 __attribute__((ext_vector_type(8)));
typedef float float4_t __attribute__((ext_vector_type(4)));
typedef float f32x16 __attribute__((ext_vector_type(16)));
typedef unsigned short ushort_t;

#define BH   32
#define N_   2048
#define D_   64
#define NCH  32
#define KV_ELEMS (BH * N_ * D_)
// d_ws: Kf [0,8M) | Vf [8M,16M) | mskT [16M,16.5M)
#define OFF_VF  (KV_ELEMS * 2)
#define OFF_MSK (KV_ELEMS * 4)
#define QSCALE 0.18033688f      // 0.125*log2(e): exp(s/8) == exp2(s*QSCALE)

__device__ __forceinline__ unsigned pack_bf16(float a, float b) {
  union { float f; unsigned u; } ua{a}, ub{b};
  return __builtin_amdgcn_perm(ub.u + 0x8000u, ua.u + 0x8000u, 0x07060302u);
}

__device__ __forceinline__ void gload_lds16(const ushort_t* g, ushort_t* l) {
  // async global->LDS, 16B/lane, lane-linear dest (fragment-linear layout)
  __builtin_amdgcn_global_load_lds(
      (const __attribute__((address_space(1))) unsigned int*)(g),
      (__attribute__((address_space(3))) unsigned int*)(l), 16, 0, 0);
}

// ---------------- prep v7: 32x32-MFMA fragment-linear Kf/Vf + transposed bitmask ----
// Kf group g = nt*4+ks  : lane(hi,l32) -> K[nt*32+l32][ks*16+hi*8+j]   (S^T A-frag)
// Vf group g = nt*4+dt*2+ksp: lane -> V[nt*32+phi][dt*32+l32],
//   phi(ksp,hi,j) = (ksp*2+(j>>2))*8 + hi*4 + (j&3)   (PV B-frag, key-permuted to
//   match the in-register P A-frag assembled from S^T's C-layout regs)
// mskT[c][row]: coalesced per-q-row u64 mask words in attn.
__global__ __launch_bounds__(256) void prep_kernel(
    const float* __restrict__ K, const float* __restrict__ V,
    const int* __restrict__ adj, ushort_t* __restrict__ Kf,
    ushort_t* __restrict__ Vf, unsigned long long* __restrict__ msk) {
  __shared__ __align__(16) float Tc[64 * 68];
  const int blk = blockIdx.x, t = threadIdx.x;

  if (blk < 2048) {
    const bool isK = blk < 1024;
    const int b = isK ? blk : blk - 1024;
    const float* src = (isK ? K : V) + (b >> 5) * (N_ * D_) + (b & 31) * 64 * D_;
#pragma unroll
    for (int i = 0; i < 4; ++i) {
      int idx = i * 256 + t;
      int row = idx >> 4, c4 = (idx & 15) * 4;
      *(float4_t*)&Tc[row * 68 + c4] = *(const float4_t*)(src + row * D_ + c4);
    }
    __syncthreads();
    ushort_t* dst = (isK ? Kf : Vf) + b * 4096;
#pragma unroll
    for (int e = 0; e < 2; ++e) {
      int u = t * 2 + e;
      int g = u >> 6, lane = u & 63;
      int hi = lane >> 5, l32 = lane & 31;
      float v[8];
      if (isK) {
        int nt = g >> 2, ks = g & 3;
        const float* rp = &Tc[(nt * 32 + l32) * 68 + ks * 16 + hi * 8];
        float4_t a = *(const float4_t*)(rp);
        float4_t bq = *(const float4_t*)(rp + 4);
#pragma unroll
        for (int j = 0; j < 4; ++j) { v[j] = a[j]; v[4 + j] = bq[j]; }
      } else {
        int nt = g >> 2, dt = (g >> 1) & 1, ksp = g & 1;
#pragma unroll
        for (int j = 0; j < 8; ++j) {
          int key = (ksp * 2 + (j >> 2)) * 8 + hi * 4 + (j & 3);
          v[j] = Tc[(nt * 32 + key) * 68 + dt * 32 + l32];
        }
      }
      union { short8 s; unsigned u4[4]; } h;
      h.u4[0] = pack_bf16(v[0], v[1]); h.u4[1] = pack_bf16(v[2], v[3]);
      h.u4[2] = pack_bf16(v[4], v[5]); h.u4[3] = pack_bf16(v[6], v[7]);
      *(short8*)(dst + u * 8) = h.s;
    }
  } else {
    const int row = (blk - 2048) * 4 + (t >> 6);
    const int lane = t & 63;
    unsigned long long keep = 0;
#pragma unroll 8
    for (int i = 0; i < 32; ++i) {
      int a = adj[row * N_ + i * 64 + lane];
      unsigned long long b = __ballot(a > 0);
      if (lane == i) keep = b;
    }
    if (lane < 32) msk[(size_t)lane * 2048 + row] = keep;   // mskT[c][row]
  }
}

// -------- main v7: 32x32x16 MFMA, swapped QK^T (S^T), in-register P (no P-LDS),
//          wave pairs split keys (nt halves), 8 b128 LDS reads/chunk/wave --------
__global__ __launch_bounds__(512, 4) void attn_main(
    const float* __restrict__ Q, const ushort_t* __restrict__ Kf,
    const ushort_t* __restrict__ Vf, const unsigned long long* __restrict__ msk,
    float* __restrict__ O) {
  __shared__ __align__(16) ushort_t kv[2][8192];   // [K 8KB | V 8KB] x2, 32KB
  __shared__ float xbuf[4][17][64];                // epilogue cross-wave reduce, 17KB

  const int t    = threadIdx.x;
  const int w    = t >> 6;                  // 0..7
  const int lane = t & 63;
  const int l32  = lane & 31;
  const int hi   = lane >> 5;
  const int pair = w >> 1;                  // 0..3 : 32-row tile
  const int nt   = w & 1;                   // key half (cols nt*32..+31)
  const int bh   = blockIdx.x & (BH - 1);
  const int qt   = blockIdx.x >> 5;         // 0..15
  const int base = bh * (N_ * D_);
  const int trow0 = qt * 128 + pair * 32;   // 32 q-rows per wave pair

  const ushort_t* Kfb = Kf + (bh * 32) * 4096;
  const ushort_t* Vfb = Vf + (bh * 32) * 4096;
  const unsigned long long* mrow = msk + (trow0 + l32);   // + c*2048 per chunk

  // Q B-frags for S^T = mfma(K, Q): B[k=d][n=q]: n=l32 (q-row), k=ks*16+hi*8+j
  short8 qf[4];
#pragma unroll
  for (int ks = 0; ks < 4; ++ks) {
    const float* qp = Q + base + (trow0 + l32) * D_ + ks * 16 + hi * 8;
    float4_t f0 = *(const float4_t*)(qp);
    float4_t f1 = *(const float4_t*)(qp + 4);
    union { short8 s; unsigned u[4]; } h;
    h.u[0] = pack_bf16(f0[0] * QSCALE, f0[1] * QSCALE);
    h.u[1] = pack_bf16(f0[2] * QSCALE, f0[3] * QSCALE);
    h.u[2] = pack_bf16(f1[0] * QSCALE, f1[1] * QSCALE);
    h.u[3] = pack_bf16(f1[2] * QSCALE, f1[3] * QSCALE);
    qf[ks] = h.s;
  }

  f32x16 oacc0, oacc1;        // O C-layout: col=l32 (+dt*32), row=(reg&3)+8*(reg>>2)+4*hi
  float osum = 0.f;           // partial rowsum for q = l32 over this wave's keys
#pragma unroll
  for (int i = 0; i < 16; ++i) { oacc0[i] = 0.f; oacc1[i] = 0.f; }

  const int fo = lane * 8;    // lane-linear fragment offset (16B/lane)

  // cooperative stage of chunk c into kv[nb]: wave w moves bytes [w*2KB, +2KB)
#define STAGE(nb, c)                                                          \
  do {                                                                        \
    const ushort_t* _s = (w < 4 ? Kfb + (c)*4096 + w * 1024                   \
                                : Vfb + (c)*4096 + (w - 4) * 1024) + lane * 8;\
    ushort_t* _d = &kv[nb][w * 1024];                                         \
    gload_lds16(_s, _d);                                                      \
    gload_lds16(_s + 512, _d + 512);                                          \
  } while (0)

  STAGE(0, 0);   // prologue

#pragma unroll 2
  for (int c = 0; c < NCH; ++c) {
    const int cur = c & 1;
    // implicit vmcnt(0)+lgkmcnt(0) drain: stage(c) landed for ALL waves
    __syncthreads();

    unsigned long long mw = mrow[(size_t)c * 2048];   // coalesced u64/lane

    if (c + 1 < NCH) STAGE(cur ^ 1, c + 1);

    const ushort_t* kb = &kv[cur][0];
    const ushort_t* vb = &kv[cur][4096];

    // ---- S^T = K Q^T : C-layout => lane holds q=l32, keys=(reg&3)+8*(reg>>2)+4*hi
    f32x16 sacc;
#pragma unroll
    for (int i = 0; i < 16; ++i) sacc[i] = 0.f;
#pragma unroll
    for (int ks = 0; ks < 4; ++ks) {
      short8 kfr = *(const short8*)(kb + (nt * 4 + ks) * 512 + fo);
      sacc = __builtin_amdgcn_mfma_f32_32x32x16_bf16(kfr, qf[ks], sacc, 0, 0, 0);
    }

    // ---- mask + exp (all in-register; bits at static positions after one shift)
    unsigned half = (unsigned)(nt ? (mw >> 32) : mw);
    half >>= (hi << 2);
    float p[16];
#pragma unroll
    for (int reg = 0; reg < 16; ++reg) {
      const int pos = (reg & 3) + 8 * (reg >> 2);        // static
      int sm = ((int)(half << (31 - pos))) >> 31;        // sext(bit pos)
      union { float f; unsigned u; } e;
      e.f = __builtin_amdgcn_exp2f(sacc[reg]);
      e.u &= (unsigned)sm;
      p[reg] = e.f;
      osum += e.f;
    }

    // ---- P -> bf16 A-frags in-register (key permutation matches Vf's phi) ----
    union { short8 s; unsigned u[4]; } pa0, pa1;
#pragma unroll
    for (int jj = 0; jj < 4; ++jj) {
      int r = (jj >> 1) * 4 + (jj & 1) * 2;
      pa0.u[jj] = pack_bf16(p[r], p[r + 1]);
      pa1.u[jj] = pack_bf16(p[8 + r], p[8 + r + 1]);
    }

    // ---- O += P V over this wave's 32 keys (2 ksp slices x 2 d-tiles) ----
    {
      short8 v00 = *(const short8*)(vb + (nt * 4 + 0) * 512 + fo);  // dt0,ksp0
      short8 v01 = *(const short8*)(vb + (nt * 4 + 1) * 512 + fo);  // dt0,ksp1
      short8 v10 = *(const short8*)(vb + (nt * 4 + 2) * 512 + fo);  // dt1,ksp0
      short8 v11 = *(const short8*)(vb + (nt * 4 + 3) * 512 + fo);  // dt1,ksp1
      oacc0 = __builtin_amdgcn_mfma_f32_32x32x16_bf16(pa0.s, v00, oacc0, 0, 0, 0);
      oacc0 = __builtin_amdgcn_mfma_f32_32x32x16_bf16(pa1.s, v01, oacc0, 0, 0, 0);
      oacc1 = __builtin_amdgcn_mfma_f32_32x32x16_bf16(pa0.s, v10, oacc1, 0, 0, 0);
      oacc1 = __builtin_amdgcn_mfma_f32_32x32x16_bf16(pa1.s, v11, oacc1, 0, 0, 0);
    }
  }

  // ---- epilogue: combine hi halves, then nt halves (LDS), normalize, store ----
  osum += __shfl_xor(osum, 32);    // full rowsum over this wave's 32 keys, q=l32

  __syncthreads();
  if (nt) {
#pragma unroll
    for (int reg = 0; reg < 16; ++reg) xbuf[pair][reg][lane] = oacc0[reg];
    xbuf[pair][16][lane] = osum;
  }
  __syncthreads();
  float inv = 0.f;
  if (!nt) {
    inv = 1.f / (osum + xbuf[pair][16][lane]);          // for q = l32
#pragma unroll
    for (int reg = 0; reg < 16; ++reg) oacc0[reg] += xbuf[pair][reg][lane];
  }
  __syncthreads();
  if (nt) {
#pragma unroll
    for (int reg = 0; reg < 16; ++reg) xbuf[pair][reg][lane] = oacc1[reg];
  }
  __syncthreads();
  if (!nt) {
#pragma unroll
    for (int reg = 0; reg < 16; ++reg) {
      int qo = (reg & 3) + 8 * (reg >> 2) + 4 * hi;     // output q-row
      float iv = __shfl(inv, qo);                       // inv lives at lane qo
      float o0 = (oacc0[reg]) * iv;
      float o1 = (oacc1[reg] + xbuf[pair][reg][lane]) * iv;
      O[base + (trow0 + qo) * D_ + l32]      = o0;
      O[base + (trow0 + qo) * D_ + 32 + l32] = o1;
    }
  }
}

extern "C" void kernel_launch(void* const* d_in, const int* in_sizes, int n_in,
                              void* d_out, int out_size, void* d_ws, size_t ws_size,
                              hipStream_t stream) {
  const float* Q  = (const float*)d_in[0];
  const float* K  = (const float*)d_in[1];
  const float* V  = (const float*)d_in[2];
  const int* adj  = (const int*)d_in[3];
  float* O        = (float*)d_out;
  ushort_t* Kf    = (ushort_t*)d_ws;
  ushort_t* Vf    = (ushort_t*)((char*)d_ws + OFF_VF);
  unsigned long long* msk = (unsigned long long*)((char*)d_ws + OFF_MSK);

  prep_kernel<<<2560, 256, 0, stream>>>(K, V, adj, Kf, Vf, msk);
  attn_main<<<512, 512, 0, stream>>>(Q, Kf, Vf, msk, O);   // 4096 waves, 16/CU
}

// Round 9
// 152.316 us; speedup vs baseline: 1.1752x; 1.0122x over previous
//
#include <hip/hip_runtime.h>
#include <math.h>

typedef short short8 __attribute__((ext_vector_type(8)));
typedef float float4_t __attribute__((ext_vector_type(4)));
typedef float f32x16 __attribute__((ext_vector_type(16)));
typedef unsigned short ushort_t;

#define BH   32
#define N_   2048
#define D_   64
#define NCH  32
#define KV_ELEMS (BH * N_ * D_)
// d_ws: Kf [0,8M) | Vf [8M,16M) | mskT [16M,16.5M)
#define OFF_VF  (KV_ELEMS * 2)
#define OFF_MSK (KV_ELEMS * 4)
#define QSCALE 0.18033688f      // 0.125*log2(e): exp(s/8) == exp2(s*QSCALE)

__device__ __forceinline__ unsigned pack_bf16(float a, float b) {
  union { float f; unsigned u; } ua{a}, ub{b};
  return __builtin_amdgcn_perm(ub.u + 0x8000u, ua.u + 0x8000u, 0x07060302u);
}

__device__ __forceinline__ unsigned cvt_pk_bf16(float a, float b) {
  // single-inst packed f32->bf16 (lo = a, hi = b); no builtin on gfx950
  unsigned r;
  asm("v_cvt_pk_bf16_f32 %0, %1, %2" : "=v"(r) : "v"(a), "v"(b));
  return r;
}

__device__ __forceinline__ void gload_lds16(const ushort_t* g, ushort_t* l) {
  // async global->LDS, 16B/lane, lane-linear dest (fragment-linear layout)
  __builtin_amdgcn_global_load_lds(
      (const __attribute__((address_space(1))) unsigned int*)(g),
      (__attribute__((address_space(3))) unsigned int*)(l), 16, 0, 0);
}

// ---------------- prep v7 (verified r8, unchanged): 32x32 fragment-linear Kf/Vf + mskT ----
// Kf group g = nt*4+ks  : lane(hi,l32) -> K[nt*32+l32][ks*16+hi*8+j]   (S^T A-frag)
// Vf group g = nt*4+dt*2+ksp: lane -> V[nt*32+phi][dt*32+l32],
//   phi(ksp,hi,j) = (ksp*2+(j>>2))*8 + hi*4 + (j&3)   (PV B-frag, key-permuted)
// mskT[c][row]: coalesced per-q-row u64 mask words in attn.
__global__ __launch_bounds__(256) void prep_kernel(
    const float* __restrict__ K, const float* __restrict__ V,
    const int* __restrict__ adj, ushort_t* __restrict__ Kf,
    ushort_t* __restrict__ Vf, unsigned long long* __restrict__ msk) {
  __shared__ __align__(16) float Tc[64 * 68];
  const int blk = blockIdx.x, t = threadIdx.x;

  if (blk < 2048) {
    const bool isK = blk < 1024;
    const int b = isK ? blk : blk - 1024;
    const float* src = (isK ? K : V) + (b >> 5) * (N_ * D_) + (b & 31) * 64 * D_;
#pragma unroll
    for (int i = 0; i < 4; ++i) {
      int idx = i * 256 + t;
      int row = idx >> 4, c4 = (idx & 15) * 4;
      *(float4_t*)&Tc[row * 68 + c4] = *(const float4_t*)(src + row * D_ + c4);
    }
    __syncthreads();
    ushort_t* dst = (isK ? Kf : Vf) + b * 4096;
#pragma unroll
    for (int e = 0; e < 2; ++e) {
      int u = t * 2 + e;
      int g = u >> 6, lane = u & 63;
      int hi = lane >> 5, l32 = lane & 31;
      float v[8];
      if (isK) {
        int nt = g >> 2, ks = g & 3;
        const float* rp = &Tc[(nt * 32 + l32) * 68 + ks * 16 + hi * 8];
        float4_t a = *(const float4_t*)(rp);
        float4_t bq = *(const float4_t*)(rp + 4);
#pragma unroll
        for (int j = 0; j < 4; ++j) { v[j] = a[j]; v[4 + j] = bq[j]; }
      } else {
        int nt = g >> 2, dt = (g >> 1) & 1, ksp = g & 1;
#pragma unroll
        for (int j = 0; j < 8; ++j) {
          int key = (ksp * 2 + (j >> 2)) * 8 + hi * 4 + (j & 3);
          v[j] = Tc[(nt * 32 + key) * 68 + dt * 32 + l32];
        }
      }
      union { short8 s; unsigned u4[4]; } h;
      h.u4[0] = pack_bf16(v[0], v[1]); h.u4[1] = pack_bf16(v[2], v[3]);
      h.u4[2] = pack_bf16(v[4], v[5]); h.u4[3] = pack_bf16(v[6], v[7]);
      *(short8*)(dst + u * 8) = h.s;
    }
  } else {
    const int row = (blk - 2048) * 4 + (t >> 6);
    const int lane = t & 63;
    unsigned long long keep = 0;
#pragma unroll 8
    for (int i = 0; i < 32; ++i) {
      int a = adj[row * N_ + i * 64 + lane];
      unsigned long long b = __ballot(a > 0);
      if (lane == i) keep = b;
    }
    if (lane < 32) msk[(size_t)lane * 2048 + row] = keep;   // mskT[c][row]
  }
}

// -------- main v8: v7 + VALU-trimmed P path --------
//   * P->bf16 via v_cvt_pk_bf16_f32 (1 inst/pair vs 3)
//   * row-sum via MFMA-ones into osacc (kills 16 dependent v_add/chunk;
//     osacc rows align with oacc rows -> shfl-free epilogue)
__global__ __launch_bounds__(512, 4) void attn_main(
    const float* __restrict__ Q, const ushort_t* __restrict__ Kf,
    const ushort_t* __restrict__ Vf, const unsigned long long* __restrict__ msk,
    float* __restrict__ O) {
  __shared__ __align__(16) ushort_t kv[2][8192];   // [K 8KB | V 8KB] x2, 32KB
  __shared__ float xbuf[4][32][64];                // epilogue cross-wave reduce, 32KB

  const int t    = threadIdx.x;
  const int w    = t >> 6;                  // 0..7
  const int lane = t & 63;
  const int l32  = lane & 31;
  const int hi   = lane >> 5;
  const int pair = w >> 1;                  // 0..3 : 32-row tile
  const int nt   = w & 1;                   // key half (cols nt*32..+31)
  const int bh   = blockIdx.x & (BH - 1);
  const int qt   = blockIdx.x >> 5;         // 0..15
  const int base = bh * (N_ * D_);
  const int trow0 = qt * 128 + pair * 32;   // 32 q-rows per wave pair

  const ushort_t* Kfb = Kf + (bh * 32) * 4096;
  const ushort_t* Vfb = Vf + (bh * 32) * 4096;
  const unsigned long long* mrow = msk + (trow0 + l32);   // + c*2048 per chunk

  // Q B-frags for S^T = mfma(K, Q): B[k=d][n=q]: n=l32 (q-row), k=ks*16+hi*8+j
  short8 qf[4];
#pragma unroll
  for (int ks = 0; ks < 4; ++ks) {
    const float* qp = Q + base + (trow0 + l32) * D_ + ks * 16 + hi * 8;
    float4_t f0 = *(const float4_t*)(qp);
    float4_t f1 = *(const float4_t*)(qp + 4);
    union { short8 s; unsigned u[4]; } h;
    h.u[0] = pack_bf16(f0[0] * QSCALE, f0[1] * QSCALE);
    h.u[1] = pack_bf16(f0[2] * QSCALE, f0[3] * QSCALE);
    h.u[2] = pack_bf16(f1[0] * QSCALE, f1[1] * QSCALE);
    h.u[3] = pack_bf16(f1[2] * QSCALE, f1[3] * QSCALE);
    qf[ks] = h.s;
  }

  // constant ones B-fragment (bf16 1.0) for rowsum-via-MFMA
  short8 ones;
#pragma unroll
  for (int j = 0; j < 8; ++j) ones[j] = (short)0x3F80;

  f32x16 oacc0, oacc1;  // O C-layout: col=l32 (+dt*32), row=(reg&3)+8*(reg>>2)+4*hi
  f32x16 osacc;         // rowsum of masked P, same row mapping as oacc (cols equal)
#pragma unroll
  for (int i = 0; i < 16; ++i) { oacc0[i] = 0.f; oacc1[i] = 0.f; osacc[i] = 0.f; }

  const int fo = lane * 8;    // lane-linear fragment offset (16B/lane)

  // cooperative stage of chunk c into kv[nb]: wave w moves bytes [w*2KB, +2KB)
#define STAGE(nb, c)                                                          \
  do {                                                                        \
    const ushort_t* _s = (w < 4 ? Kfb + (c)*4096 + w * 1024                   \
                                : Vfb + (c)*4096 + (w - 4) * 1024) + lane * 8;\
    ushort_t* _d = &kv[nb][w * 1024];                                         \
    gload_lds16(_s, _d);                                                      \
    gload_lds16(_s + 512, _d + 512);                                          \
  } while (0)

  STAGE(0, 0);   // prologue

#pragma unroll 2
  for (int c = 0; c < NCH; ++c) {
    const int cur = c & 1;
    // implicit vmcnt(0)+lgkmcnt(0) drain: stage(c) landed for ALL waves
    __syncthreads();

    unsigned long long mw = mrow[(size_t)c * 2048];   // coalesced u64/lane

    if (c + 1 < NCH) STAGE(cur ^ 1, c + 1);

    const ushort_t* kb = &kv[cur][0];
    const ushort_t* vb = &kv[cur][4096];

    // ---- S^T = K Q^T : C-layout => lane holds q=l32, keys=(reg&3)+8*(reg>>2)+4*hi
    f32x16 sacc;
#pragma unroll
    for (int i = 0; i < 16; ++i) sacc[i] = 0.f;
#pragma unroll
    for (int ks = 0; ks < 4; ++ks) {
      short8 kfr = *(const short8*)(kb + (nt * 4 + ks) * 512 + fo);
      sacc = __builtin_amdgcn_mfma_f32_32x32x16_bf16(kfr, qf[ks], sacc, 0, 0, 0);
    }

    // ---- mask + exp (in-register; bits at static positions after one shift)
    unsigned half = (unsigned)(nt ? (mw >> 32) : mw);
    half >>= (hi << 2);
    float p[16];
#pragma unroll
    for (int reg = 0; reg < 16; ++reg) {
      const int pos = (reg & 3) + 8 * (reg >> 2);        // static
      int sm = ((int)(half << (31 - pos))) >> 31;        // sext(bit pos)
      union { float f; unsigned u; } e;
      e.f = __builtin_amdgcn_exp2f(sacc[reg]);
      e.u &= (unsigned)sm;
      p[reg] = e.f;
    }

    // ---- P -> bf16 A-frags in-register (key permutation matches Vf's phi) ----
    union { short8 s; unsigned u[4]; } pa0, pa1;
#pragma unroll
    for (int jj = 0; jj < 4; ++jj) {
      int r = (jj >> 1) * 4 + (jj & 1) * 2;
      pa0.u[jj] = cvt_pk_bf16(p[r], p[r + 1]);
      pa1.u[jj] = cvt_pk_bf16(p[8 + r], p[8 + r + 1]);
    }

    // ---- O += P V (2 ksp slices x 2 d-tiles); rowsum += P * ones ----
    {
      short8 v00 = *(const short8*)(vb + (nt * 4 + 0) * 512 + fo);  // dt0,ksp0
      short8 v01 = *(const short8*)(vb + (nt * 4 + 1) * 512 + fo);  // dt0,ksp1
      short8 v10 = *(const short8*)(vb + (nt * 4 + 2) * 512 + fo);  // dt1,ksp0
      short8 v11 = *(const short8*)(vb + (nt * 4 + 3) * 512 + fo);  // dt1,ksp1
      oacc0 = __builtin_amdgcn_mfma_f32_32x32x16_bf16(pa0.s, v00, oacc0, 0, 0, 0);
      oacc0 = __builtin_amdgcn_mfma_f32_32x32x16_bf16(pa1.s, v01, oacc0, 0, 0, 0);
      oacc1 = __builtin_amdgcn_mfma_f32_32x32x16_bf16(pa0.s, v10, oacc1, 0, 0, 0);
      oacc1 = __builtin_amdgcn_mfma_f32_32x32x16_bf16(pa1.s, v11, oacc1, 0, 0, 0);
      osacc = __builtin_amdgcn_mfma_f32_32x32x16_bf16(pa0.s, ones, osacc, 0, 0, 0);
      osacc = __builtin_amdgcn_mfma_f32_32x32x16_bf16(pa1.s, ones, osacc, 0, 0, 0);
    }
  }

  // ---- epilogue: combine nt halves via LDS, normalize per-reg (no shfl) ----
  __syncthreads();
  if (nt) {
#pragma unroll
    for (int reg = 0; reg < 16; ++reg) {
      xbuf[pair][reg][lane]      = oacc0[reg];
      xbuf[pair][16 + reg][lane] = osacc[reg];
    }
  }
  __syncthreads();
  float invv[16];
  if (!nt) {
#pragma unroll
    for (int reg = 0; reg < 16; ++reg) {
      invv[reg] = 1.f / (osacc[reg] + xbuf[pair][16 + reg][lane]);
      oacc0[reg] = (oacc0[reg] + xbuf[pair][reg][lane]) * invv[reg];
    }
  }
  __syncthreads();
  if (nt) {
#pragma unroll
    for (int reg = 0; reg < 16; ++reg) xbuf[pair][reg][lane] = oacc1[reg];
  }
  __syncthreads();
  if (!nt) {
#pragma unroll
    for (int reg = 0; reg < 16; ++reg) {
      int qo = (reg & 3) + 8 * (reg >> 2) + 4 * hi;     // output q-row
      O[base + (trow0 + qo) * D_ + l32]      = oacc0[reg];
      O[base + (trow0 + qo) * D_ + 32 + l32] =
          (oacc1[reg] + xbuf[pair][reg][lane]) * invv[reg];
    }
  }
}

extern "C" void kernel_launch(void* const* d_in, const int* in_sizes, int n_in,
                              void* d_out, int out_size, void* d_ws, size_t ws_size,
                              hipStream_t stream) {
  const float* Q  = (const float*)d_in[0];
  const float* K  = (const float*)d_in[1];
  const float* V  = (const float*)d_in[2];
  const int* adj  = (const int*)d_in[3];
  float* O        = (float*)d_out;
  ushort_t* Kf    = (ushort_t*)d_ws;
  ushort_t* Vf    = (ushort_t*)((char*)d_ws + OFF_VF);
  unsigned long long* msk = (unsigned long long*)((char*)d_ws + OFF_MSK);

  prep_kernel<<<2560, 256, 0, stream>>>(K, V, adj, Kf, Vf, msk);
  attn_main<<<512, 512, 0, stream>>>(Q, Kf, Vf, msk, O);   // 4096 waves, 16/CU
}